// Round 8
// baseline (76.001 us; speedup 1.0000x reference)
//
#include <hip/hip_runtime.h>
#include <math.h>

#define EPSF 1e-12f
#define DD 768
#define LL 576

typedef unsigned short u16;
typedef __attribute__((ext_vector_type(8))) short bf16x8;
typedef __attribute__((ext_vector_type(4))) float f32x4;

__device__ __forceinline__ u16 bf16h(float v) {
  unsigned u = __float_as_uint(v);
  return (u16)((u + 0x7FFFu + ((u >> 16) & 1u)) >> 16);
}

// split 8 floats -> packed hi uint4, lo uint4 (bf16 RNE, lo = v - hi)
__device__ __forceinline__ void split8(const float* v, uint4& ph, uint4& pl) {
  unsigned h[8], lo[8];
#pragma unroll
  for (int i = 0; i < 8; ++i) {
    unsigned u = __float_as_uint(v[i]);
    unsigned r = (u + 0x7FFFu + ((u >> 16) & 1u)) >> 16;
    h[i] = r;
    float rest = v[i] - __uint_as_float(r << 16);
    unsigned u2 = __float_as_uint(rest);
    lo[i] = (u2 + 0x7FFFu + ((u2 >> 16) & 1u)) >> 16;
  }
  ph = make_uint4(h[0] | (h[1] << 16), h[2] | (h[3] << 16),
                  h[4] | (h[5] << 16), h[6] | (h[7] << 16));
  pl = make_uint4(lo[0] | (lo[1] << 16), lo[2] | (lo[3] << 16),
                  lo[4] | (lo[5] << 16), lo[6] | (lo[7] << 16));
}

// split 4 floats -> packed hi uint2, lo uint2
__device__ __forceinline__ void split4(const float* v, uint2& ph, uint2& pl) {
  unsigned h[4], lo[4];
#pragma unroll
  for (int i = 0; i < 4; ++i) {
    unsigned u = __float_as_uint(v[i]);
    unsigned r = (u + 0x7FFFu + ((u >> 16) & 1u)) >> 16;
    h[i] = r;
    float rest = v[i] - __uint_as_float(r << 16);
    unsigned u2 = __float_as_uint(rest);
    lo[i] = (u2 + 0x7FFFu + ((u2 >> 16) & 1u)) >> 16;
  }
  ph = make_uint2(h[0] | (h[1] << 16), h[2] | (h[3] << 16));
  pl = make_uint2(lo[0] | (lo[1] << 16), lo[2] | (lo[3] << 16));
}

// Layout probe: D1 = (bcast m-label) x (ones) -> 32*row ; D2 = (ones) x
// (bcast n-label) -> 32*col. True (row,col) per acc reg, any convention.
__device__ __forceinline__ void probe_layout(int lane, int* rowz, int* colz) {
  bf16x8 va, v1;
  const short ml = (short)bf16h((float)(lane & 15));
  const short on = (short)0x3F80;  // bf16(1.0)
#pragma unroll
  for (int e = 0; e < 8; ++e) { va[e] = ml; v1[e] = on; }
  f32x4 z = {0.f, 0.f, 0.f, 0.f};
  f32x4 D1 = __builtin_amdgcn_mfma_f32_16x16x32_bf16(va, v1, z, 0, 0, 0);
  f32x4 D2 = __builtin_amdgcn_mfma_f32_16x16x32_bf16(v1, va, z, 0, 0, 0);
#pragma unroll
  for (int r = 0; r < 4; ++r) {
    rowz[r] = (int)(D1[r] * 0.03125f + 0.5f);
    colz[r] = (int)(D2[r] * 0.03125f + 0.5f);
  }
}

// ---------------------------------------------------------------------------
// kW: pre-split W into bf16 hi/lo A-fragments, fragment-major.
// ---------------------------------------------------------------------------
__global__ __launch_bounds__(256) void kW(const float* __restrict__ w,
                                          u16* __restrict__ wfH,
                                          u16* __restrict__ wfL) {
  const int s = blockIdx.x;  // 0..23
  const int t = threadIdx.x;
  const int strip = t >> 6, lane = t & 63;
  const int k = strip * 16 + (lane & 15);
  const int d = s * 32 + (lane >> 4) * 8;
  float v[8];
  *(float4*)&v[0] = *(const float4*)(w + k * DD + d);
  *(float4*)&v[4] = *(const float4*)(w + k * DD + d + 4);
  uint4 ph, pl;
  split8(v, ph, pl);
  const size_t o = ((size_t)(strip * 24 + s) * 64 + lane) * 8;
  *(uint4*)(wfH + o) = ph;
  *(uint4*)(wfL + o) = pl;
}

// ---------------------------------------------------------------------------
// kA pipeline helpers
// ---------------------------------------------------------------------------
__device__ __forceinline__ void kA_stage(float (*rawb)[36], int xd, int xl,
                                         const float4& p, float* ssq4) {
  *(float4*)&rawb[xd][xl] = p;
  ssq4[0] = fmaf(p.x, p.x, ssq4[0]);
  ssq4[1] = fmaf(p.y, p.y, ssq4[1]);
  ssq4[2] = fmaf(p.z, p.z, ssq4[2]);
  ssq4[3] = fmaf(p.w, p.w, ssq4[3]);
}

__device__ __forceinline__ void kA_transpose(const float (*rawb)[36],
                                             u16 (*XhB)[40], u16 (*XlB)[40],
                                             int wv, int half, int tl) {
  float v[4];
#pragma unroll
  for (int j = 0; j < 4; ++j) v[j] = rawb[wv * 8 + half * 4 + j][tl];
  uint2 ph, pl;
  split4(v, ph, pl);
  const int pb = (wv ^ ((tl >> 3) & 3)) * 8 + half * 4;
  *(uint2*)&XhB[tl][pb] = ph;
  *(uint2*)&XlB[tl][pb] = pl;
}

__device__ __forceinline__ void kA_mfma(const u16 (*XhB)[40], const u16 (*XlB)[40],
                                        int lane, const bf16x8& Ah,
                                        const bf16x8& Al, f32x4* acc) {
#pragma unroll
  for (int lt = 0; lt < 2; ++lt) {
    const int bl = lt * 16 + (lane & 15);
    const int pb = ((lane >> 4) ^ ((bl >> 3) & 3)) * 8;
    bf16x8 Bh = *(const bf16x8*)&XhB[bl][pb];
    bf16x8 Bl = *(const bf16x8*)&XlB[bl][pb];
    acc[lt] = __builtin_amdgcn_mfma_f32_16x16x32_bf16(Ah, Bh, acc[lt], 0, 0, 0);
    acc[lt] = __builtin_amdgcn_mfma_f32_16x16x32_bf16(Ah, Bl, acc[lt], 0, 0, 0);
    acc[lt] = __builtin_amdgcn_mfma_f32_16x16x32_bf16(Al, Bh, acc[lt], 0, 0, 0);
  }
}

// ---------------------------------------------------------------------------
// kA: per (n, 32-l tile): logits = W @ X via split-bf16 MFMA.
// SINGLE-BARRIER software pipeline: interval i = {mfma(i-2) | transpose(i-1)
// | stage(i)} on double-buffered raw / Xh,Xl.  stage(s)->raw[s&1];
// transpose(s): raw[s&1]->X[s&1]; mfma(s): X[s&1]. All cross-thread deps
// cross >=1 barrier (disjoint parities within an interval).
// ---------------------------------------------------------------------------
__global__ __launch_bounds__(256) void kA(const float* __restrict__ x,
                                          const u16* __restrict__ wfH,
                                          const u16* __restrict__ wfL,
                                          u16* __restrict__ attH,
                                          u16* __restrict__ attL) {
  __shared__ __align__(16) float raw[2][32][36];  // 9216 B (Ls aliases both)
  __shared__ __align__(16) u16 Xh[2][32][40];     // 5120 B
  __shared__ __align__(16) u16 Xl[2][32][40];     // 5120 B
  float (*Ls)[36] = (float(*)[36])raw;            // [64][36] == sizeof(raw)
  __shared__ float red8[8][32];
  __shared__ float colinv[32], colmax[32], colscale[32];

  const int b = blockIdx.x;
  const int n = b / 18, l0 = (b % 18) * 32;
  const int t = threadIdx.x;
  const int wv = t >> 6, lane = t & 63;

  int rowz[4], colz[4];
  probe_layout(lane, rowz, colz);

  f32x4 z = {0.f, 0.f, 0.f, 0.f};
  f32x4 acc[2] = {z, z};
  float ssq4[4] = {0.f, 0.f, 0.f, 0.f};

  const int xd = t >> 3;        // 0..31 staging row
  const int xl = (t & 7) * 4;   // staging l quad
  const int tl = lane & 31;     // transpose l
  const int half = lane >> 5;   // transpose d-half

  const float* xbase = x + (size_t)n * DD * LL + l0;
  const u16* wfHp = wfH + ((size_t)wv * 24 * 64 + lane) * 8;
  const u16* wfLp = wfL + ((size_t)wv * 24 * 64 + lane) * 8;

  float4 pre = *(const float4*)(xbase + (size_t)xd * LL + xl);  // chunk 0
  bf16x8 AhN, AlN;

  // interval 0: stage(0)
  kA_stage(raw[0], xd, xl, pre, ssq4);
  pre = *(const float4*)(xbase + (size_t)(32 + xd) * LL + xl);  // chunk 1
  __syncthreads();
  // interval 1: transpose(0) + stage(1) + prefetch wf[0], chunk 2
  AhN = *(const bf16x8*)(wfHp);
  AlN = *(const bf16x8*)(wfLp);
  kA_transpose(raw[0], Xh[0], Xl[0], wv, half, tl);
  kA_stage(raw[1], xd, xl, pre, ssq4);
  pre = *(const float4*)(xbase + (size_t)(64 + xd) * LL + xl);  // chunk 2

  // steady: intervals 2..23
  for (int i = 2; i < 24; ++i) {
    __syncthreads();
    const bf16x8 AhC = AhN, AlC = AlN;
    AhN = *(const bf16x8*)(wfHp + (size_t)(i - 1) * 512);
    AlN = *(const bf16x8*)(wfLp + (size_t)(i - 1) * 512);
    const float4 cur = pre;
    if (i < 23)
      pre = *(const float4*)(xbase + (size_t)((i + 1) * 32 + xd) * LL + xl);
    kA_stage(raw[i & 1], xd, xl, cur, ssq4);
    kA_transpose(raw[(i - 1) & 1], Xh[(i - 1) & 1], Xl[(i - 1) & 1], wv, half, tl);
    kA_mfma(Xh[i & 1], Xl[i & 1], lane, AhC, AlC, acc);
  }
  __syncthreads();
  // interval 24: mfma(22) + transpose(23) + prefetch wf[23]
  {
    const bf16x8 AhC = AhN, AlC = AlN;
    AhN = *(const bf16x8*)(wfHp + (size_t)23 * 512);
    AlN = *(const bf16x8*)(wfLp + (size_t)23 * 512);
    kA_transpose(raw[1], Xh[1], Xl[1], wv, half, tl);
    kA_mfma(Xh[0], Xl[0], lane, AhC, AlC, acc);
  }
  __syncthreads();
  // interval 25: mfma(23)
  kA_mfma(Xh[1], Xl[1], lane, AhN, AlN, acc);

  // ssq reduce across xd-within-wave (lane bits 3,4,5); cg = lane&7
#pragma unroll
  for (int i = 0; i < 4; ++i) {
    ssq4[i] += __shfl_xor(ssq4[i], 8, 64);
    ssq4[i] += __shfl_xor(ssq4[i], 16, 64);
    ssq4[i] += __shfl_xor(ssq4[i], 32, 64);
  }
  if (lane < 8) {
#pragma unroll
    for (int i = 0; i < 4; ++i) red8[wv][lane * 4 + i] = ssq4[i];
  }
  __syncthreads();  // red8 ready; guards Ls scatter vs last MFMA/transpose
  if (t < 32)
    colinv[t] =
        1.f / fmaxf(sqrtf(red8[0][t] + red8[1][t] + red8[2][t] + red8[3][t]), EPSF);
  // scatter raw logits using PROBED positions (Ls aliases dead staging pool)
#pragma unroll
  for (int lt = 0; lt < 2; ++lt)
#pragma unroll
    for (int r = 0; r < 4; ++r)
      Ls[wv * 16 + rowz[r]][lt * 16 + colz[r]] = acc[lt][r];
  __syncthreads();

  // softmax over k per column; thread (q=t>>5, cl=t&31) owns 8 k's
  const int cl = t & 31, q = t >> 5;
  const float cinv = colinv[cl];
  float sv[8];
  float m = -1e30f;
#pragma unroll
  for (int i = 0; i < 8; ++i) {
    const float vv = Ls[q * 8 + i][cl] * cinv;
    sv[i] = vv;
    m = fmaxf(m, vv);
  }
  red8[q][cl] = m;
  __syncthreads();
  if (t < 32) {
    float mm = red8[0][t];
#pragma unroll
    for (int j = 1; j < 8; ++j) mm = fmaxf(mm, red8[j][t]);
    colmax[t] = mm;
  }
  __syncthreads();
  const float M = colmax[cl];
  float ssum = 0.f;
#pragma unroll
  for (int i = 0; i < 8; ++i) {
    const float e = __expf(sv[i] - M);
    sv[i] = e;
    ssum += e;
  }
  red8[q][cl] = ssum;
  __syncthreads();
  if (t < 32) {
    float ss = red8[0][t];
#pragma unroll
    for (int j = 1; j < 8; ++j) ss += red8[j][t];
    colscale[t] = colinv[t] / ss;
  }
  __syncthreads();
  const float cs = colscale[cl];
  u16* aH = attH + (size_t)n * 64 * LL + l0 + cl;
  u16* aL = attL + (size_t)n * 64 * LL + l0 + cl;
#pragma unroll
  for (int i = 0; i < 8; ++i) {
    const int k = q * 8 + i;
    const float e = sv[i] * cs;
    unsigned u = __float_as_uint(e);
    unsigned r = (u + 0x7FFFu + ((u >> 16) & 1u)) >> 16;
    const float rest = e - __uint_as_float(r << 16);
    aH[(size_t)k * LL] = (u16)r;
    aL[(size_t)k * LL] = bf16h(rest);
  }
}

// ---------------------------------------------------------------------------
// kB: per (n, 64-d tile): out[k][d] = sum_l att'[k][l] * x[d][l], split-bf16
// MFMA, reg-prefetched staging. Probe-based output positions. Fused
// per-(k, d-tile) sumsq partials -> part[b][k] (deterministic).
// ---------------------------------------------------------------------------
__global__ __launch_bounds__(256) void kB(const float* __restrict__ x,
                                          const u16* __restrict__ attH,
                                          const u16* __restrict__ attL,
                                          float* __restrict__ out,
                                          float* __restrict__ part) {
  __shared__ __align__(16) u16 AH[64][40];
  __shared__ __align__(16) u16 AL[64][40];
  __shared__ __align__(16) u16 Xh[64][40];
  __shared__ __align__(16) u16 Xl[64][40];
  const int b = blockIdx.x;
  const int n = b / 12, d0 = (b % 12) * 64;
  const int t = threadIdx.x;
  const int wv = t >> 6, lane = t & 63;

  int rowz[4], colz[4];
  probe_layout(lane, rowz, colz);

  f32x4 z = {0.f, 0.f, 0.f, 0.f};
  f32x4 acc[4] = {z, z, z, z};

  const int rk = t >> 2;       // staging row 0..63
  const int lb = (t & 3) * 8;  // l offset 0,8,16,24

  const u16* aHb = attH + ((size_t)n * 64 + rk) * LL + lb;
  const u16* aLb = attL + ((size_t)n * 64 + rk) * LL + lb;
  const float* xb = x + ((size_t)n * DD + d0 + rk) * LL + lb;

  uint4 pAH = *(const uint4*)aHb;
  uint4 pAL = *(const uint4*)aLb;
  float4 pX0 = *(const float4*)xb;
  float4 pX1 = *(const float4*)(xb + 4);

  for (int s = 0; s < 18; ++s) {
    __syncthreads();  // prev MFMA reads done
    *(uint4*)&AH[rk][lb] = pAH;
    *(uint4*)&AL[rk][lb] = pAL;
    {
      float v[8] = {pX0.x, pX0.y, pX0.z, pX0.w, pX1.x, pX1.y, pX1.z, pX1.w};
      uint4 ph, pl;
      split8(v, ph, pl);
      *(uint4*)&Xh[rk][lb] = ph;
      *(uint4*)&Xl[rk][lb] = pl;
    }
    if (s < 17) {
      const int lo = (s + 1) * 32;
      pAH = *(const uint4*)(aHb + lo);
      pAL = *(const uint4*)(aLb + lo);
      pX0 = *(const float4*)(xb + lo);
      pX1 = *(const float4*)(xb + lo + 4);
    }
    __syncthreads();  // staged
    const int ar = wv * 16 + (lane & 15);
    const int ab = (lane >> 4) * 8;
    bf16x8 Ah = *(const bf16x8*)&AH[ar][ab];
    bf16x8 Alo = *(const bf16x8*)&AL[ar][ab];
#pragma unroll
    for (int dt = 0; dt < 4; ++dt) {
      const int br = dt * 16 + (lane & 15);
      bf16x8 Bh = *(const bf16x8*)&Xh[br][ab];
      bf16x8 Bl = *(const bf16x8*)&Xl[br][ab];
      acc[dt] = __builtin_amdgcn_mfma_f32_16x16x32_bf16(Ah, Bh, acc[dt], 0, 0, 0);
      acc[dt] = __builtin_amdgcn_mfma_f32_16x16x32_bf16(Ah, Bl, acc[dt], 0, 0, 0);
      acc[dt] = __builtin_amdgcn_mfma_f32_16x16x32_bf16(Alo, Bh, acc[dt], 0, 0, 0);
    }
  }

  // store raw out using PROBED positions
  float* ob = out + ((size_t)n * 64 + wv * 16) * DD + d0;
#pragma unroll
  for (int dt = 0; dt < 4; ++dt)
#pragma unroll
    for (int r = 0; r < 4; ++r)
      ob[(size_t)rowz[r] * DD + dt * 16 + colz[r]] = acc[dt][r];

  // fused per-(k, d-tile) sumsq partial (deterministic, no atomics)
#pragma unroll
  for (int r = 0; r < 4; ++r) {
    float s = 0.f;
#pragma unroll
    for (int dt = 0; dt < 4; ++dt) s = fmaf(acc[dt][r], acc[dt][r], s);
    s += __shfl_xor(s, 1, 64);
    s += __shfl_xor(s, 2, 64);
    s += __shfl_xor(s, 4, 64);
    s += __shfl_xor(s, 8, 64);
    if ((lane & 15) == 0)
      part[(size_t)b * 64 + wv * 16 + rowz[r]] = s;
  }
}

// ---------------------------------------------------------------------------
// Epilogue. Global norm over 64 unit rows == sqrt(64) exactly (up to fp32
// dust in the reference, ~1e-7 rel), so ginv = 1/8 and no cross-k reduce.
// ---------------------------------------------------------------------------
__global__ __launch_bounds__(64) void kC2(const float* __restrict__ part,
                                          float* __restrict__ scale) {
  const int n = blockIdx.x;
  const int t = threadIdx.x;  // = k
  float ss = 0.f;
#pragma unroll
  for (int j = 0; j < 12; ++j) ss += part[(size_t)(n * 12 + j) * 64 + t];
  scale[n * 64 + t] = 0.125f / fmaxf(sqrtf(ss), EPSF);
}

__global__ __launch_bounds__(256) void kC3(float* __restrict__ out,
                                           const float* __restrict__ scale) {
  const int i = blockIdx.x * 256 + threadIdx.x;
  const int row = i / 192;
  const float s = scale[row];
  float4 v = ((float4*)out)[i];
  v.x *= s; v.y *= s; v.z *= s; v.w *= s;
  ((float4*)out)[i] = v;
}

// ---------------------------------------------------------------------------
extern "C" void kernel_launch(void* const* d_in, const int* in_sizes, int n_in,
                              void* d_out, int out_size, void* d_ws, size_t ws_size,
                              hipStream_t stream) {
  const float* x = (const float*)d_in[0];  // [64,768,24,24]
  const float* w = (const float*)d_in[1];  // [64,768]
  float* out = (float*)d_out;              // [64, 64*768]

  u16* attH = (u16*)d_ws;                    // [64,64,576] bf16 hi
  u16* attL = attH + (size_t)2359296;        // lo plane
  u16* wfH = attL + (size_t)2359296;         // W fragments hi [4*24*64*8]
  u16* wfL = wfH + 49152;                    // W fragments lo
  float* part = (float*)(wfL + 49152);       // [768][64] sumsq partials
  float* scale = part + 49152;               // [4096]

  kW<<<24, 256, 0, stream>>>(w, wfH, wfL);
  kA<<<1152, 256, 0, stream>>>(x, wfH, wfL, attH, attL);
  kB<<<768, 256, 0, stream>>>(x, attH, attL, out, part);
  kC2<<<64, 64, 0, stream>>>(part, scale);
  kC3<<<3072, 256, 0, stream>>>(out, scale);
}

// Round 9
// 67.382 us; speedup vs baseline: 1.1279x; 1.1279x over previous
//
#include <hip/hip_runtime.h>
#include <math.h>

#define EPSF 1e-12f
#define DD 768
#define LL 576

typedef unsigned short u16;
typedef __attribute__((ext_vector_type(8))) short bf16x8;
typedef __attribute__((ext_vector_type(4))) float f32x4;

__device__ __forceinline__ u16 bf16h(float v) {
  unsigned u = __float_as_uint(v);
  return (u16)((u + 0x7FFFu + ((u >> 16) & 1u)) >> 16);
}

// split 8 floats -> packed hi uint4, lo uint4 (bf16 RNE, lo = v - hi)
__device__ __forceinline__ void split8(const float* v, uint4& ph, uint4& pl) {
  unsigned h[8], lo[8];
#pragma unroll
  for (int i = 0; i < 8; ++i) {
    unsigned u = __float_as_uint(v[i]);
    unsigned r = (u + 0x7FFFu + ((u >> 16) & 1u)) >> 16;
    h[i] = r;
    float rest = v[i] - __uint_as_float(r << 16);
    unsigned u2 = __float_as_uint(rest);
    lo[i] = (u2 + 0x7FFFu + ((u2 >> 16) & 1u)) >> 16;
  }
  ph = make_uint4(h[0] | (h[1] << 16), h[2] | (h[3] << 16),
                  h[4] | (h[5] << 16), h[6] | (h[7] << 16));
  pl = make_uint4(lo[0] | (lo[1] << 16), lo[2] | (lo[3] << 16),
                  lo[4] | (lo[5] << 16), lo[6] | (lo[7] << 16));
}

// convert 8 floats -> packed bf16 (RNE) uint4, hi only
__device__ __forceinline__ void cvt8(const float* v, uint4& ph) {
  unsigned h[8];
#pragma unroll
  for (int i = 0; i < 8; ++i) {
    unsigned u = __float_as_uint(v[i]);
    h[i] = (u + 0x7FFFu + ((u >> 16) & 1u)) >> 16;
  }
  ph = make_uint4(h[0] | (h[1] << 16), h[2] | (h[3] << 16),
                  h[4] | (h[5] << 16), h[6] | (h[7] << 16));
}

// split 4 floats -> packed hi uint2, lo uint2
__device__ __forceinline__ void split4(const float* v, uint2& ph, uint2& pl) {
  unsigned h[4], lo[4];
#pragma unroll
  for (int i = 0; i < 4; ++i) {
    unsigned u = __float_as_uint(v[i]);
    unsigned r = (u + 0x7FFFu + ((u >> 16) & 1u)) >> 16;
    h[i] = r;
    float rest = v[i] - __uint_as_float(r << 16);
    unsigned u2 = __float_as_uint(rest);
    lo[i] = (u2 + 0x7FFFu + ((u2 >> 16) & 1u)) >> 16;
  }
  ph = make_uint2(h[0] | (h[1] << 16), h[2] | (h[3] << 16));
  pl = make_uint2(lo[0] | (lo[1] << 16), lo[2] | (lo[3] << 16));
}

// Layout probe: D1 = (bcast m-label) x (ones) -> 32*row ; D2 = (ones) x
// (bcast n-label) -> 32*col. True (row,col) per acc reg, any convention.
__device__ __forceinline__ void probe_layout(int lane, int* rowz, int* colz) {
  bf16x8 va, v1;
  const short ml = (short)bf16h((float)(lane & 15));
  const short on = (short)0x3F80;  // bf16(1.0)
#pragma unroll
  for (int e = 0; e < 8; ++e) { va[e] = ml; v1[e] = on; }
  f32x4 z = {0.f, 0.f, 0.f, 0.f};
  f32x4 D1 = __builtin_amdgcn_mfma_f32_16x16x32_bf16(va, v1, z, 0, 0, 0);
  f32x4 D2 = __builtin_amdgcn_mfma_f32_16x16x32_bf16(v1, va, z, 0, 0, 0);
#pragma unroll
  for (int r = 0; r < 4; ++r) {
    rowz[r] = (int)(D1[r] * 0.03125f + 0.5f);
    colz[r] = (int)(D2[r] * 0.03125f + 0.5f);
  }
}

// ---------------------------------------------------------------------------
// kW: pre-split W into bf16 hi/lo A-fragments, fragment-major.
// ---------------------------------------------------------------------------
__global__ __launch_bounds__(256) void kW(const float* __restrict__ w,
                                          u16* __restrict__ wfH,
                                          u16* __restrict__ wfL) {
  const int s = blockIdx.x;  // 0..23
  const int t = threadIdx.x;
  const int strip = t >> 6, lane = t & 63;
  const int k = strip * 16 + (lane & 15);
  const int d = s * 32 + (lane >> 4) * 8;
  float v[8];
  *(float4*)&v[0] = *(const float4*)(w + k * DD + d);
  *(float4*)&v[4] = *(const float4*)(w + k * DD + d + 4);
  uint4 ph, pl;
  split8(v, ph, pl);
  const size_t o = ((size_t)(strip * 24 + s) * 64 + lane) * 8;
  *(uint4*)(wfH + o) = ph;
  *(uint4*)(wfL + o) = pl;
}

// ---------------------------------------------------------------------------
// kA: per (n, 32-l tile): logits = W @ X via split-bf16 MFMA.  (round-5/7 form)
// W from precomputed fragments (global, L2-hot). X reg-prefetched one step
// ahead; LDS transpose+split once per step. Probe-based scatter; softmax.
// att' written HI-ONLY (kB precision budget analysis, round 9).
// ---------------------------------------------------------------------------
__global__ __launch_bounds__(256) void kA(const float* __restrict__ x,
                                          const u16* __restrict__ wfH,
                                          const u16* __restrict__ wfL,
                                          u16* __restrict__ attH) {
  __shared__ __align__(16) char pool[9728];
  float (*raw)[36] = (float(*)[36])pool;       // [32d][32l+4] fp32
  u16 (*Xh)[40] = (u16(*)[40])(pool + 4608);   // [32l][32d swizzled]+pad
  u16 (*Xl)[40] = (u16(*)[40])(pool + 7168);
  float (*Ls)[36] = (float(*)[36])pool;        // [64k][32l+4] aliases pool
  __shared__ float red8[8][32];
  __shared__ float colinv[32], colmax[32], colscale[32];

  const int b = blockIdx.x;
  const int n = b / 18, l0 = (b % 18) * 32;
  const int t = threadIdx.x;
  const int wv = t >> 6, lane = t & 63;

  int rowz[4], colz[4];
  probe_layout(lane, rowz, colz);

  f32x4 z = {0.f, 0.f, 0.f, 0.f};
  f32x4 acc[2] = {z, z};
  float ssq4[4] = {0.f, 0.f, 0.f, 0.f};

  const int xd = t >> 3;        // 0..31 staging row
  const int xl = (t & 7) * 4;   // staging l quad
  const int tl = lane & 31;     // transpose l
  const int half = lane >> 5;   // transpose d-half

  const float* xbase = x + (size_t)n * DD * LL + l0;
  const u16* wfHp = wfH + ((size_t)wv * 24 * 64 + lane) * 8;
  const u16* wfLp = wfL + ((size_t)wv * 24 * 64 + lane) * 8;

  float4 pre = *(const float4*)(xbase + (size_t)xd * LL + xl);

  for (int s = 0; s < 24; ++s) {
    __syncthreads();  // prev transpose raw-reads + prev MFMA Xh/Xl-reads done
    *(float4*)&raw[xd][xl] = pre;
    ssq4[0] = fmaf(pre.x, pre.x, ssq4[0]);
    ssq4[1] = fmaf(pre.y, pre.y, ssq4[1]);
    ssq4[2] = fmaf(pre.z, pre.z, ssq4[2]);
    ssq4[3] = fmaf(pre.w, pre.w, ssq4[3]);
    if (s < 23)
      pre = *(const float4*)(xbase + (size_t)((s + 1) * 32 + xd) * LL + xl);
    bf16x8 Ah = *(const bf16x8*)(wfHp + (size_t)s * 512);
    bf16x8 Alo = *(const bf16x8*)(wfLp + (size_t)s * 512);
    __syncthreads();  // raw ready
    // transpose+split: thread (dg=wv, half, tl) handles 4 d-elements
    {
      float v[4];
#pragma unroll
      for (int j = 0; j < 4; ++j) v[j] = raw[wv * 8 + half * 4 + j][tl];
      uint2 ph, pl;
      split4(v, ph, pl);
      const int pb = (wv ^ ((tl >> 3) & 3)) * 8 + half * 4;
      *(uint2*)&Xh[tl][pb] = ph;
      *(uint2*)&Xl[tl][pb] = pl;
    }
    __syncthreads();  // Xh/Xl ready
#pragma unroll
    for (int lt = 0; lt < 2; ++lt) {
      const int bl = lt * 16 + (lane & 15);
      const int pb = ((lane >> 4) ^ ((bl >> 3) & 3)) * 8;
      bf16x8 Bh = *(const bf16x8*)&Xh[bl][pb];
      bf16x8 Bl = *(const bf16x8*)&Xl[bl][pb];
      acc[lt] = __builtin_amdgcn_mfma_f32_16x16x32_bf16(Ah, Bh, acc[lt], 0, 0, 0);
      acc[lt] = __builtin_amdgcn_mfma_f32_16x16x32_bf16(Ah, Bl, acc[lt], 0, 0, 0);
      acc[lt] = __builtin_amdgcn_mfma_f32_16x16x32_bf16(Alo, Bh, acc[lt], 0, 0, 0);
    }
  }

  // ssq reduce across xd-within-wave (lane bits 3,4,5); cg = lane&7
#pragma unroll
  for (int i = 0; i < 4; ++i) {
    ssq4[i] += __shfl_xor(ssq4[i], 8, 64);
    ssq4[i] += __shfl_xor(ssq4[i], 16, 64);
    ssq4[i] += __shfl_xor(ssq4[i], 32, 64);
  }
  if (lane < 8) {
#pragma unroll
    for (int i = 0; i < 4; ++i) red8[wv][lane * 4 + i] = ssq4[i];
  }
  __syncthreads();  // also guards Ls scatter vs last MFMA reads
  if (t < 32)
    colinv[t] =
        1.f / fmaxf(sqrtf(red8[0][t] + red8[1][t] + red8[2][t] + red8[3][t]), EPSF);
  // scatter raw logits using PROBED positions (Ls aliases dead staging pool)
#pragma unroll
  for (int lt = 0; lt < 2; ++lt)
#pragma unroll
    for (int r = 0; r < 4; ++r)
      Ls[wv * 16 + rowz[r]][lt * 16 + colz[r]] = acc[lt][r];
  __syncthreads();

  // softmax over k per column; thread (q=t>>5, cl=t&31) owns 8 k's
  const int cl = t & 31, q = t >> 5;
  const float cinv = colinv[cl];
  float sv[8];
  float m = -1e30f;
#pragma unroll
  for (int i = 0; i < 8; ++i) {
    const float vv = Ls[q * 8 + i][cl] * cinv;
    sv[i] = vv;
    m = fmaxf(m, vv);
  }
  red8[q][cl] = m;
  __syncthreads();
  if (t < 32) {
    float mm = red8[0][t];
#pragma unroll
    for (int j = 1; j < 8; ++j) mm = fmaxf(mm, red8[j][t]);
    colmax[t] = mm;
  }
  __syncthreads();
  const float M = colmax[cl];
  float ssum = 0.f;
#pragma unroll
  for (int i = 0; i < 8; ++i) {
    const float e = __expf(sv[i] - M);
    sv[i] = e;
    ssum += e;
  }
  red8[q][cl] = ssum;
  __syncthreads();
  if (t < 32) {
    float ss = red8[0][t];
#pragma unroll
    for (int j = 1; j < 8; ++j) ss += red8[j][t];
    colscale[t] = colinv[t] / ss;
  }
  __syncthreads();
  const float cs = colscale[cl];
  u16* aH = attH + (size_t)n * 64 * LL + l0 + cl;
#pragma unroll
  for (int i = 0; i < 8; ++i) {
    const int k = q * 8 + i;
    aH[(size_t)k * LL] = bf16h(sv[i] * cs);
  }
}

// ---------------------------------------------------------------------------
// kB: per (n, 64-d tile): out[k][d] = sum_l att'[k][l] * x[d][l].
// HI-ONLY bf16 MFMA (1 MFMA per dt; precision budget round 9). Reg-prefetched
// staging. Probe-based output positions. Fused per-(k, d-tile) sumsq partials
// -> part[b][k] (deterministic).
// ---------------------------------------------------------------------------
__global__ __launch_bounds__(256) void kB(const float* __restrict__ x,
                                          const u16* __restrict__ attH,
                                          float* __restrict__ out,
                                          float* __restrict__ part) {
  __shared__ __align__(16) u16 AH[64][40];
  __shared__ __align__(16) u16 Xh[64][40];
  const int b = blockIdx.x;
  const int n = b / 12, d0 = (b % 12) * 64;
  const int t = threadIdx.x;
  const int wv = t >> 6, lane = t & 63;

  int rowz[4], colz[4];
  probe_layout(lane, rowz, colz);

  f32x4 z = {0.f, 0.f, 0.f, 0.f};
  f32x4 acc[4] = {z, z, z, z};

  const int rk = t >> 2;       // staging row 0..63
  const int lb = (t & 3) * 8;  // l offset 0,8,16,24

  const u16* aHb = attH + ((size_t)n * 64 + rk) * LL + lb;
  const float* xb = x + ((size_t)n * DD + d0 + rk) * LL + lb;

  uint4 pAH = *(const uint4*)aHb;
  float4 pX0 = *(const float4*)xb;
  float4 pX1 = *(const float4*)(xb + 4);

  for (int s = 0; s < 18; ++s) {
    __syncthreads();  // prev MFMA reads done
    *(uint4*)&AH[rk][lb] = pAH;
    {
      float v[8] = {pX0.x, pX0.y, pX0.z, pX0.w, pX1.x, pX1.y, pX1.z, pX1.w};
      uint4 ph;
      cvt8(v, ph);
      *(uint4*)&Xh[rk][lb] = ph;
    }
    if (s < 17) {
      const int lo = (s + 1) * 32;
      pAH = *(const uint4*)(aHb + lo);
      pX0 = *(const float4*)(xb + lo);
      pX1 = *(const float4*)(xb + lo + 4);
    }
    __syncthreads();  // staged
    const int ar = wv * 16 + (lane & 15);
    const int ab = (lane >> 4) * 8;
    bf16x8 Ah = *(const bf16x8*)&AH[ar][ab];
#pragma unroll
    for (int dt = 0; dt < 4; ++dt) {
      const int br = dt * 16 + (lane & 15);
      bf16x8 Bh = *(const bf16x8*)&Xh[br][ab];
      acc[dt] = __builtin_amdgcn_mfma_f32_16x16x32_bf16(Ah, Bh, acc[dt], 0, 0, 0);
    }
  }

  // store raw out using PROBED positions
  float* ob = out + ((size_t)n * 64 + wv * 16) * DD + d0;
#pragma unroll
  for (int dt = 0; dt < 4; ++dt)
#pragma unroll
    for (int r = 0; r < 4; ++r)
      ob[(size_t)rowz[r] * DD + dt * 16 + colz[r]] = acc[dt][r];

  // fused per-(k, d-tile) sumsq partial (deterministic, no atomics)
#pragma unroll
  for (int r = 0; r < 4; ++r) {
    float s = 0.f;
#pragma unroll
    for (int dt = 0; dt < 4; ++dt) s = fmaf(acc[dt][r], acc[dt][r], s);
    s += __shfl_xor(s, 1, 64);
    s += __shfl_xor(s, 2, 64);
    s += __shfl_xor(s, 4, 64);
    s += __shfl_xor(s, 8, 64);
    if ((lane & 15) == 0)
      part[(size_t)b * 64 + wv * 16 + rowz[r]] = s;
  }
}

// ---------------------------------------------------------------------------
// Epilogue. Global norm over 64 unit rows == sqrt(64), so ginv = 1/8.
// ---------------------------------------------------------------------------
__global__ __launch_bounds__(64) void kC2(const float* __restrict__ part,
                                          float* __restrict__ scale) {
  const int n = blockIdx.x;
  const int t = threadIdx.x;  // = k
  float ss = 0.f;
#pragma unroll
  for (int j = 0; j < 12; ++j) ss += part[(size_t)(n * 12 + j) * 64 + t];
  scale[n * 64 + t] = 0.125f / fmaxf(sqrtf(ss), EPSF);
}

__global__ __launch_bounds__(256) void kC3(float* __restrict__ out,
                                           const float* __restrict__ scale) {
  const int i = blockIdx.x * 256 + threadIdx.x;
  const int row = i / 192;
  const float s = scale[row];
  float4 v = ((float4*)out)[i];
  v.x *= s; v.y *= s; v.z *= s; v.w *= s;
  ((float4*)out)[i] = v;
}

// ---------------------------------------------------------------------------
extern "C" void kernel_launch(void* const* d_in, const int* in_sizes, int n_in,
                              void* d_out, int out_size, void* d_ws, size_t ws_size,
                              hipStream_t stream) {
  const float* x = (const float*)d_in[0];  // [64,768,24,24]
  const float* w = (const float*)d_in[1];  // [64,768]
  float* out = (float*)d_out;              // [64, 64*768]

  u16* attH = (u16*)d_ws;                    // [64,64,576] bf16 hi only
  u16* wfH = attH + (size_t)2359296;         // W fragments hi [4*24*64*8]
  u16* wfL = wfH + 49152;                    // W fragments lo
  float* part = (float*)(wfL + 49152);       // [768][64] sumsq partials
  float* scale = part + 49152;               // [4096]

  kW<<<24, 256, 0, stream>>>(w, wfH, wfL);
  kA<<<1152, 256, 0, stream>>>(x, wfH, wfL, attH);
  kB<<<768, 256, 0, stream>>>(x, attH, out, part);
  kC2<<<64, 64, 0, stream>>>(part, scale);
  kC3<<<3072, 256, 0, stream>>>(out, scale);
}

// Round 10
// 62.812 us; speedup vs baseline: 1.2100x; 1.0728x over previous
//
#include <hip/hip_runtime.h>
#include <math.h>

#define EPSF 1e-12f
#define DD 768
#define LL 576

typedef unsigned short u16;
typedef __attribute__((ext_vector_type(8))) short bf16x8;
typedef __attribute__((ext_vector_type(4))) float f32x4;

__device__ __forceinline__ u16 bf16h(float v) {
  unsigned u = __float_as_uint(v);
  return (u16)((u + 0x7FFFu + ((u >> 16) & 1u)) >> 16);
}

// split 8 floats -> packed hi uint4, lo uint4 (bf16 RNE, lo = v - hi)
__device__ __forceinline__ void split8(const float* v, uint4& ph, uint4& pl) {
  unsigned h[8], lo[8];
#pragma unroll
  for (int i = 0; i < 8; ++i) {
    unsigned u = __float_as_uint(v[i]);
    unsigned r = (u + 0x7FFFu + ((u >> 16) & 1u)) >> 16;
    h[i] = r;
    float rest = v[i] - __uint_as_float(r << 16);
    unsigned u2 = __float_as_uint(rest);
    lo[i] = (u2 + 0x7FFFu + ((u2 >> 16) & 1u)) >> 16;
  }
  ph = make_uint4(h[0] | (h[1] << 16), h[2] | (h[3] << 16),
                  h[4] | (h[5] << 16), h[6] | (h[7] << 16));
  pl = make_uint4(lo[0] | (lo[1] << 16), lo[2] | (lo[3] << 16),
                  lo[4] | (lo[5] << 16), lo[6] | (lo[7] << 16));
}

// convert 8 floats -> packed bf16 (RNE) uint4, hi only
__device__ __forceinline__ void cvt8(const float* v, uint4& ph) {
  unsigned h[8];
#pragma unroll
  for (int i = 0; i < 8; ++i) {
    unsigned u = __float_as_uint(v[i]);
    h[i] = (u + 0x7FFFu + ((u >> 16) & 1u)) >> 16;
  }
  ph = make_uint4(h[0] | (h[1] << 16), h[2] | (h[3] << 16),
                  h[4] | (h[5] << 16), h[6] | (h[7] << 16));
}

// convert 4 floats -> packed bf16 (RNE) uint2, hi only
__device__ __forceinline__ void cvt4(const float* v, uint2& ph) {
  unsigned h[4];
#pragma unroll
  for (int i = 0; i < 4; ++i) {
    unsigned u = __float_as_uint(v[i]);
    h[i] = (u + 0x7FFFu + ((u >> 16) & 1u)) >> 16;
  }
  ph = make_uint2(h[0] | (h[1] << 16), h[2] | (h[3] << 16));
}

// Layout probe: D1 = (bcast m-label) x (ones) -> 32*row ; D2 = (ones) x
// (bcast n-label) -> 32*col. True (row,col) per acc reg, any convention.
__device__ __forceinline__ void probe_layout(int lane, int* rowz, int* colz) {
  bf16x8 va, v1;
  const short ml = (short)bf16h((float)(lane & 15));
  const short on = (short)0x3F80;  // bf16(1.0)
#pragma unroll
  for (int e = 0; e < 8; ++e) { va[e] = ml; v1[e] = on; }
  f32x4 z = {0.f, 0.f, 0.f, 0.f};
  f32x4 D1 = __builtin_amdgcn_mfma_f32_16x16x32_bf16(va, v1, z, 0, 0, 0);
  f32x4 D2 = __builtin_amdgcn_mfma_f32_16x16x32_bf16(v1, va, z, 0, 0, 0);
#pragma unroll
  for (int r = 0; r < 4; ++r) {
    rowz[r] = (int)(D1[r] * 0.03125f + 0.5f);
    colz[r] = (int)(D2[r] * 0.03125f + 0.5f);
  }
}

// ---------------------------------------------------------------------------
// kW: pre-split W into bf16 hi/lo A-fragments, fragment-major.
// ---------------------------------------------------------------------------
__global__ __launch_bounds__(256) void kW(const float* __restrict__ w,
                                          u16* __restrict__ wfH,
                                          u16* __restrict__ wfL) {
  const int s = blockIdx.x;  // 0..23
  const int t = threadIdx.x;
  const int strip = t >> 6, lane = t & 63;
  const int k = strip * 16 + (lane & 15);
  const int d = s * 32 + (lane >> 4) * 8;
  float v[8];
  *(float4*)&v[0] = *(const float4*)(w + k * DD + d);
  *(float4*)&v[4] = *(const float4*)(w + k * DD + d + 4);
  uint4 ph, pl;
  split8(v, ph, pl);
  const size_t o = ((size_t)(strip * 24 + s) * 64 + lane) * 8;
  *(uint4*)(wfH + o) = ph;
  *(uint4*)(wfL + o) = pl;
}

// ---------------------------------------------------------------------------
// kA: per (n, 32-l tile): logits = W @ X. W split-bf16 (hi+lo), X HI-ONLY
// (round-10 precision budget: X truncation adds ~0.003 logit error, fp32
// MFMA accum). X reg-prefetched; LDS transpose+cvt once per step; 2 MFMA
// per l-tile. Probe-based scatter; softmax; att' hi-only.
// ---------------------------------------------------------------------------
__global__ __launch_bounds__(256) void kA(const float* __restrict__ x,
                                          const u16* __restrict__ wfH,
                                          const u16* __restrict__ wfL,
                                          u16* __restrict__ attH) {
  __shared__ __align__(16) char pool[9216];
  float (*raw)[36] = (float(*)[36])pool;       // [32d][32l+4] fp32, 4608B
  u16 (*Xh)[40] = (u16(*)[40])(pool + 4608);   // [32l][32d swizzled]+pad
  float (*Ls)[36] = (float(*)[36])pool;        // [64k][32l+4] aliases pool
  __shared__ float red8[8][32];
  __shared__ float colinv[32], colmax[32], colscale[32];

  const int b = blockIdx.x;
  const int n = b / 18, l0 = (b % 18) * 32;
  const int t = threadIdx.x;
  const int wv = t >> 6, lane = t & 63;

  int rowz[4], colz[4];
  probe_layout(lane, rowz, colz);

  f32x4 z = {0.f, 0.f, 0.f, 0.f};
  f32x4 acc[2] = {z, z};
  float ssq4[4] = {0.f, 0.f, 0.f, 0.f};

  const int xd = t >> 3;        // 0..31 staging row
  const int xl = (t & 7) * 4;   // staging l quad
  const int tl = lane & 31;     // transpose l
  const int half = lane >> 5;   // transpose d-half

  const float* xbase = x + (size_t)n * DD * LL + l0;
  const u16* wfHp = wfH + ((size_t)wv * 24 * 64 + lane) * 8;
  const u16* wfLp = wfL + ((size_t)wv * 24 * 64 + lane) * 8;

  float4 pre = *(const float4*)(xbase + (size_t)xd * LL + xl);

  for (int s = 0; s < 24; ++s) {
    __syncthreads();  // prev transpose raw-reads + prev MFMA Xh-reads done
    *(float4*)&raw[xd][xl] = pre;
    ssq4[0] = fmaf(pre.x, pre.x, ssq4[0]);
    ssq4[1] = fmaf(pre.y, pre.y, ssq4[1]);
    ssq4[2] = fmaf(pre.z, pre.z, ssq4[2]);
    ssq4[3] = fmaf(pre.w, pre.w, ssq4[3]);
    if (s < 23)
      pre = *(const float4*)(xbase + (size_t)((s + 1) * 32 + xd) * LL + xl);
    bf16x8 Ah = *(const bf16x8*)(wfHp + (size_t)s * 512);
    bf16x8 Alo = *(const bf16x8*)(wfLp + (size_t)s * 512);
    __syncthreads();  // raw ready
    // transpose+cvt: thread (dg=wv, half, tl) handles 4 d-elements (hi only)
    {
      float v[4];
#pragma unroll
      for (int j = 0; j < 4; ++j) v[j] = raw[wv * 8 + half * 4 + j][tl];
      uint2 ph;
      cvt4(v, ph);
      const int pb = (wv ^ ((tl >> 3) & 3)) * 8 + half * 4;
      *(uint2*)&Xh[tl][pb] = ph;
    }
    __syncthreads();  // Xh ready
#pragma unroll
    for (int lt = 0; lt < 2; ++lt) {
      const int bl = lt * 16 + (lane & 15);
      const int pb = ((lane >> 4) ^ ((bl >> 3) & 3)) * 8;
      bf16x8 Bh = *(const bf16x8*)&Xh[bl][pb];
      acc[lt] = __builtin_amdgcn_mfma_f32_16x16x32_bf16(Ah, Bh, acc[lt], 0, 0, 0);
      acc[lt] = __builtin_amdgcn_mfma_f32_16x16x32_bf16(Alo, Bh, acc[lt], 0, 0, 0);
    }
  }

  // ssq reduce across xd-within-wave (lane bits 3,4,5); cg = lane&7
#pragma unroll
  for (int i = 0; i < 4; ++i) {
    ssq4[i] += __shfl_xor(ssq4[i], 8, 64);
    ssq4[i] += __shfl_xor(ssq4[i], 16, 64);
    ssq4[i] += __shfl_xor(ssq4[i], 32, 64);
  }
  if (lane < 8) {
#pragma unroll
    for (int i = 0; i < 4; ++i) red8[wv][lane * 4 + i] = ssq4[i];
  }
  __syncthreads();  // also guards Ls scatter vs last MFMA reads
  if (t < 32)
    colinv[t] =
        1.f / fmaxf(sqrtf(red8[0][t] + red8[1][t] + red8[2][t] + red8[3][t]), EPSF);
  // scatter raw logits using PROBED positions (Ls aliases dead staging pool)
#pragma unroll
  for (int lt = 0; lt < 2; ++lt)
#pragma unroll
    for (int r = 0; r < 4; ++r)
      Ls[wv * 16 + rowz[r]][lt * 16 + colz[r]] = acc[lt][r];
  __syncthreads();

  // softmax over k per column; thread (q=t>>5, cl=t&31) owns 8 k's
  const int cl = t & 31, q = t >> 5;
  const float cinv = colinv[cl];
  float sv[8];
  float m = -1e30f;
#pragma unroll
  for (int i = 0; i < 8; ++i) {
    const float vv = Ls[q * 8 + i][cl] * cinv;
    sv[i] = vv;
    m = fmaxf(m, vv);
  }
  red8[q][cl] = m;
  __syncthreads();
  if (t < 32) {
    float mm = red8[0][t];
#pragma unroll
    for (int j = 1; j < 8; ++j) mm = fmaxf(mm, red8[j][t]);
    colmax[t] = mm;
  }
  __syncthreads();
  const float M = colmax[cl];
  float ssum = 0.f;
#pragma unroll
  for (int i = 0; i < 8; ++i) {
    const float e = __expf(sv[i] - M);
    sv[i] = e;
    ssum += e;
  }
  red8[q][cl] = ssum;
  __syncthreads();
  if (t < 32) {
    float ss = red8[0][t];
#pragma unroll
    for (int j = 1; j < 8; ++j) ss += red8[j][t];
    colscale[t] = colinv[t] / ss;
  }
  __syncthreads();
  const float cs = colscale[cl];
  u16* aH = attH + (size_t)n * 64 * LL + l0 + cl;
#pragma unroll
  for (int i = 0; i < 8; ++i) {
    const int k = q * 8 + i;
    aH[(size_t)k * LL] = bf16h(sv[i] * cs);
  }
}

// ---------------------------------------------------------------------------
// kB: per (n, 64-d tile): out[k][d] = sum_l att'[k][l] * x[d][l].
// HI-ONLY bf16 MFMA. Reg-prefetched staging. Probe-based output positions.
// Fused per-(k, d-tile) sumsq partials -> part[b][k] (deterministic).
// ---------------------------------------------------------------------------
__global__ __launch_bounds__(256) void kB(const float* __restrict__ x,
                                          const u16* __restrict__ attH,
                                          float* __restrict__ out,
                                          float* __restrict__ part) {
  __shared__ __align__(16) u16 AH[64][40];
  __shared__ __align__(16) u16 Xh[64][40];
  const int b = blockIdx.x;
  const int n = b / 12, d0 = (b % 12) * 64;
  const int t = threadIdx.x;
  const int wv = t >> 6, lane = t & 63;

  int rowz[4], colz[4];
  probe_layout(lane, rowz, colz);

  f32x4 z = {0.f, 0.f, 0.f, 0.f};
  f32x4 acc[4] = {z, z, z, z};

  const int rk = t >> 2;       // staging row 0..63
  const int lb = (t & 3) * 8;  // l offset 0,8,16,24

  const u16* aHb = attH + ((size_t)n * 64 + rk) * LL + lb;
  const float* xb = x + ((size_t)n * DD + d0 + rk) * LL + lb;

  uint4 pAH = *(const uint4*)aHb;
  float4 pX0 = *(const float4*)xb;
  float4 pX1 = *(const float4*)(xb + 4);

  for (int s = 0; s < 18; ++s) {
    __syncthreads();  // prev MFMA reads done
    *(uint4*)&AH[rk][lb] = pAH;
    {
      float v[8] = {pX0.x, pX0.y, pX0.z, pX0.w, pX1.x, pX1.y, pX1.z, pX1.w};
      uint4 ph;
      cvt8(v, ph);
      *(uint4*)&Xh[rk][lb] = ph;
    }
    if (s < 17) {
      const int lo = (s + 1) * 32;
      pAH = *(const uint4*)(aHb + lo);
      pX0 = *(const float4*)(xb + lo);
      pX1 = *(const float4*)(xb + lo + 4);
    }
    __syncthreads();  // staged
    const int ar = wv * 16 + (lane & 15);
    const int ab = (lane >> 4) * 8;
    bf16x8 Ah = *(const bf16x8*)&AH[ar][ab];
#pragma unroll
    for (int dt = 0; dt < 4; ++dt) {
      const int br = dt * 16 + (lane & 15);
      bf16x8 Bh = *(const bf16x8*)&Xh[br][ab];
      acc[dt] = __builtin_amdgcn_mfma_f32_16x16x32_bf16(Ah, Bh, acc[dt], 0, 0, 0);
    }
  }

  // store raw out using PROBED positions
  float* ob = out + ((size_t)n * 64 + wv * 16) * DD + d0;
#pragma unroll
  for (int dt = 0; dt < 4; ++dt)
#pragma unroll
    for (int r = 0; r < 4; ++r)
      ob[(size_t)rowz[r] * DD + dt * 16 + colz[r]] = acc[dt][r];

  // fused per-(k, d-tile) sumsq partial (deterministic, no atomics)
#pragma unroll
  for (int r = 0; r < 4; ++r) {
    float s = 0.f;
#pragma unroll
    for (int dt = 0; dt < 4; ++dt) s = fmaf(acc[dt][r], acc[dt][r], s);
    s += __shfl_xor(s, 1, 64);
    s += __shfl_xor(s, 2, 64);
    s += __shfl_xor(s, 4, 64);
    s += __shfl_xor(s, 8, 64);
    if ((lane & 15) == 0)
      part[(size_t)b * 64 + wv * 16 + rowz[r]] = s;
  }
}

// ---------------------------------------------------------------------------
// Epilogue. Global norm over 64 unit rows == sqrt(64), so ginv = 1/8.
// ---------------------------------------------------------------------------
__global__ __launch_bounds__(64) void kC2(const float* __restrict__ part,
                                          float* __restrict__ scale) {
  const int n = blockIdx.x;
  const int t = threadIdx.x;  // = k
  float ss = 0.f;
#pragma unroll
  for (int j = 0; j < 12; ++j) ss += part[(size_t)(n * 12 + j) * 64 + t];
  scale[n * 64 + t] = 0.125f / fmaxf(sqrtf(ss), EPSF);
}

__global__ __launch_bounds__(256) void kC3(float* __restrict__ out,
                                           const float* __restrict__ scale) {
  const int i = blockIdx.x * 256 + threadIdx.x;
  const int row = i / 192;
  const float s = scale[row];
  float4 v = ((float4*)out)[i];
  v.x *= s; v.y *= s; v.z *= s; v.w *= s;
  ((float4*)out)[i] = v;
}

// ---------------------------------------------------------------------------
extern "C" void kernel_launch(void* const* d_in, const int* in_sizes, int n_in,
                              void* d_out, int out_size, void* d_ws, size_t ws_size,
                              hipStream_t stream) {
  const float* x = (const float*)d_in[0];  // [64,768,24,24]
  const float* w = (const float*)d_in[1];  // [64,768]
  float* out = (float*)d_out;              // [64, 64*768]

  u16* attH = (u16*)d_ws;                    // [64,64,576] bf16 hi only
  u16* wfH = attH + (size_t)2359296;         // W fragments hi [4*24*64*8]
  u16* wfL = wfH + 49152;                    // W fragments lo
  float* part = (float*)(wfL + 49152);       // [768][64] sumsq partials
  float* scale = part + 49152;               // [4096]

  kW<<<24, 256, 0, stream>>>(w, wfH, wfL);
  kA<<<1152, 256, 0, stream>>>(x, wfH, wfL, attH);
  kB<<<768, 256, 0, stream>>>(x, attH, out, part);
  kC2<<<64, 64, 0, stream>>>(part, scale);
  kC3<<<3072, 256, 0, stream>>>(out, scale);
}

// Round 11
// 58.961 us; speedup vs baseline: 1.2890x; 1.0653x over previous
//
#include <hip/hip_runtime.h>
#include <math.h>

#define EPSF 1e-12f
#define DD 768
#define LL 576

typedef unsigned short u16;
typedef __attribute__((ext_vector_type(8))) short bf16x8;
typedef __attribute__((ext_vector_type(4))) float f32x4;

__device__ __forceinline__ u16 bf16h(float v) {
  unsigned u = __float_as_uint(v);
  return (u16)((u + 0x7FFFu + ((u >> 16) & 1u)) >> 16);
}

// convert 8 floats -> packed bf16 (RNE) uint4
__device__ __forceinline__ void cvt8(const float* v, uint4& ph) {
  unsigned h[8];
#pragma unroll
  for (int i = 0; i < 8; ++i) {
    unsigned u = __float_as_uint(v[i]);
    h[i] = (u + 0x7FFFu + ((u >> 16) & 1u)) >> 16;
  }
  ph = make_uint4(h[0] | (h[1] << 16), h[2] | (h[3] << 16),
                  h[4] | (h[5] << 16), h[6] | (h[7] << 16));
}

// convert 4 floats -> packed bf16 (RNE) uint2
__device__ __forceinline__ void cvt4(const float* v, uint2& ph) {
  unsigned h[4];
#pragma unroll
  for (int i = 0; i < 4; ++i) {
    unsigned u = __float_as_uint(v[i]);
    h[i] = (u + 0x7FFFu + ((u >> 16) & 1u)) >> 16;
  }
  ph = make_uint2(h[0] | (h[1] << 16), h[2] | (h[3] << 16));
}

// Layout probe: D1 = (bcast m-label) x (ones) -> 32*row ; D2 = (ones) x
// (bcast n-label) -> 32*col. True (row,col) per acc reg, any convention.
__device__ __forceinline__ void probe_layout(int lane, int* rowz, int* colz) {
  bf16x8 va, v1;
  const short ml = (short)bf16h((float)(lane & 15));
  const short on = (short)0x3F80;  // bf16(1.0)
#pragma unroll
  for (int e = 0; e < 8; ++e) { va[e] = ml; v1[e] = on; }
  f32x4 z = {0.f, 0.f, 0.f, 0.f};
  f32x4 D1 = __builtin_amdgcn_mfma_f32_16x16x32_bf16(va, v1, z, 0, 0, 0);
  f32x4 D2 = __builtin_amdgcn_mfma_f32_16x16x32_bf16(v1, va, z, 0, 0, 0);
#pragma unroll
  for (int r = 0; r < 4; ++r) {
    rowz[r] = (int)(D1[r] * 0.03125f + 0.5f);
    colz[r] = (int)(D2[r] * 0.03125f + 0.5f);
  }
}

// ---------------------------------------------------------------------------
// kW: pre-convert W into bf16 A-fragments (HI-ONLY, round-11), fragment-major.
// ---------------------------------------------------------------------------
__global__ __launch_bounds__(256) void kW(const float* __restrict__ w,
                                          u16* __restrict__ wfH) {
  const int s = blockIdx.x;  // 0..23
  const int t = threadIdx.x;
  const int strip = t >> 6, lane = t & 63;
  const int k = strip * 16 + (lane & 15);
  const int d = s * 32 + (lane >> 4) * 8;
  float v[8];
  *(float4*)&v[0] = *(const float4*)(w + k * DD + d);
  *(float4*)&v[4] = *(const float4*)(w + k * DD + d + 4);
  uint4 ph;
  cvt8(v, ph);
  const size_t o = ((size_t)(strip * 24 + s) * 64 + lane) * 8;
  *(uint4*)(wfH + o) = ph;
}

// ---------------------------------------------------------------------------
// kA: per (n, 32-l tile): logits = W @ X, both HI-ONLY bf16 (round-10/11
// calibrated error model: each truncation adds ~0.001 normalized-logit error,
// invisible at the output). X reg-prefetched; LDS transpose+cvt once per
// step; 2 MFMA per step. Probe-based scatter; softmax; att' hi-only.
// ---------------------------------------------------------------------------
__global__ __launch_bounds__(256) void kA(const float* __restrict__ x,
                                          const u16* __restrict__ wfH,
                                          u16* __restrict__ attH) {
  __shared__ __align__(16) char pool[9216];
  float (*raw)[36] = (float(*)[36])pool;       // [32d][32l+4] fp32, 4608B
  u16 (*Xh)[40] = (u16(*)[40])(pool + 4608);   // [32l][32d swizzled]+pad
  float (*Ls)[36] = (float(*)[36])pool;        // [64k][32l+4] aliases pool
  __shared__ float red8[8][32];
  __shared__ float colinv[32], colmax[32], colscale[32];

  const int b = blockIdx.x;
  const int n = b / 18, l0 = (b % 18) * 32;
  const int t = threadIdx.x;
  const int wv = t >> 6, lane = t & 63;

  int rowz[4], colz[4];
  probe_layout(lane, rowz, colz);

  f32x4 z = {0.f, 0.f, 0.f, 0.f};
  f32x4 acc[2] = {z, z};
  float ssq4[4] = {0.f, 0.f, 0.f, 0.f};

  const int xd = t >> 3;        // 0..31 staging row
  const int xl = (t & 7) * 4;   // staging l quad
  const int tl = lane & 31;     // transpose l
  const int half = lane >> 5;   // transpose d-half

  const float* xbase = x + (size_t)n * DD * LL + l0;
  const u16* wfHp = wfH + ((size_t)wv * 24 * 64 + lane) * 8;

  float4 pre = *(const float4*)(xbase + (size_t)xd * LL + xl);

  for (int s = 0; s < 24; ++s) {
    __syncthreads();  // prev transpose raw-reads + prev MFMA Xh-reads done
    *(float4*)&raw[xd][xl] = pre;
    ssq4[0] = fmaf(pre.x, pre.x, ssq4[0]);
    ssq4[1] = fmaf(pre.y, pre.y, ssq4[1]);
    ssq4[2] = fmaf(pre.z, pre.z, ssq4[2]);
    ssq4[3] = fmaf(pre.w, pre.w, ssq4[3]);
    if (s < 23)
      pre = *(const float4*)(xbase + (size_t)((s + 1) * 32 + xd) * LL + xl);
    bf16x8 Ah = *(const bf16x8*)(wfHp + (size_t)s * 512);
    __syncthreads();  // raw ready
    // transpose+cvt: thread (dg=wv, half, tl) handles 4 d-elements (hi only)
    {
      float v[4];
#pragma unroll
      for (int j = 0; j < 4; ++j) v[j] = raw[wv * 8 + half * 4 + j][tl];
      uint2 ph;
      cvt4(v, ph);
      const int pb = (wv ^ ((tl >> 3) & 3)) * 8 + half * 4;
      *(uint2*)&Xh[tl][pb] = ph;
    }
    __syncthreads();  // Xh ready
#pragma unroll
    for (int lt = 0; lt < 2; ++lt) {
      const int bl = lt * 16 + (lane & 15);
      const int pb = ((lane >> 4) ^ ((bl >> 3) & 3)) * 8;
      bf16x8 Bh = *(const bf16x8*)&Xh[bl][pb];
      acc[lt] = __builtin_amdgcn_mfma_f32_16x16x32_bf16(Ah, Bh, acc[lt], 0, 0, 0);
    }
  }

  // ssq reduce across xd-within-wave (lane bits 3,4,5); cg = lane&7
#pragma unroll
  for (int i = 0; i < 4; ++i) {
    ssq4[i] += __shfl_xor(ssq4[i], 8, 64);
    ssq4[i] += __shfl_xor(ssq4[i], 16, 64);
    ssq4[i] += __shfl_xor(ssq4[i], 32, 64);
  }
  if (lane < 8) {
#pragma unroll
    for (int i = 0; i < 4; ++i) red8[wv][lane * 4 + i] = ssq4[i];
  }
  __syncthreads();  // also guards Ls scatter vs last MFMA reads
  if (t < 32)
    colinv[t] =
        1.f / fmaxf(sqrtf(red8[0][t] + red8[1][t] + red8[2][t] + red8[3][t]), EPSF);
  // scatter raw logits using PROBED positions (Ls aliases dead staging pool)
#pragma unroll
  for (int lt = 0; lt < 2; ++lt)
#pragma unroll
    for (int r = 0; r < 4; ++r)
      Ls[wv * 16 + rowz[r]][lt * 16 + colz[r]] = acc[lt][r];
  __syncthreads();

  // softmax over k per column; thread (q=t>>5, cl=t&31) owns 8 k's
  const int cl = t & 31, q = t >> 5;
  const float cinv = colinv[cl];
  float sv[8];
  float m = -1e30f;
#pragma unroll
  for (int i = 0; i < 8; ++i) {
    const float vv = Ls[q * 8 + i][cl] * cinv;
    sv[i] = vv;
    m = fmaxf(m, vv);
  }
  red8[q][cl] = m;
  __syncthreads();
  if (t < 32) {
    float mm = red8[0][t];
#pragma unroll
    for (int j = 1; j < 8; ++j) mm = fmaxf(mm, red8[j][t]);
    colmax[t] = mm;
  }
  __syncthreads();
  const float M = colmax[cl];
  float ssum = 0.f;
#pragma unroll
  for (int i = 0; i < 8; ++i) {
    const float e = __expf(sv[i] - M);
    sv[i] = e;
    ssum += e;
  }
  red8[q][cl] = ssum;
  __syncthreads();
  if (t < 32) {
    float ss = red8[0][t];
#pragma unroll
    for (int j = 1; j < 8; ++j) ss += red8[j][t];
    colscale[t] = colinv[t] / ss;
  }
  __syncthreads();
  const float cs = colscale[cl];
  u16* aH = attH + (size_t)n * 64 * LL + l0 + cl;
#pragma unroll
  for (int i = 0; i < 8; ++i) {
    const int k = q * 8 + i;
    aH[(size_t)k * LL] = bf16h(sv[i] * cs);
  }
}

// ---------------------------------------------------------------------------
// kB: per (n, 64-d tile): out[k][d] = sum_l att'[k][l] * x[d][l].
// HI-ONLY bf16 MFMA. Reg-prefetched staging. Probe-based output positions.
// Fused per-(k, d-tile) sumsq partials -> part[b][k] (deterministic).
// ---------------------------------------------------------------------------
__global__ __launch_bounds__(256) void kB(const float* __restrict__ x,
                                          const u16* __restrict__ attH,
                                          float* __restrict__ out,
                                          float* __restrict__ part) {
  __shared__ __align__(16) u16 AH[64][40];
  __shared__ __align__(16) u16 Xh[64][40];
  const int b = blockIdx.x;
  const int n = b / 12, d0 = (b % 12) * 64;
  const int t = threadIdx.x;
  const int wv = t >> 6, lane = t & 63;

  int rowz[4], colz[4];
  probe_layout(lane, rowz, colz);

  f32x4 z = {0.f, 0.f, 0.f, 0.f};
  f32x4 acc[4] = {z, z, z, z};

  const int rk = t >> 2;       // staging row 0..63
  const int lb = (t & 3) * 8;  // l offset 0,8,16,24

  const u16* aHb = attH + ((size_t)n * 64 + rk) * LL + lb;
  const float* xb = x + ((size_t)n * DD + d0 + rk) * LL + lb;

  uint4 pAH = *(const uint4*)aHb;
  float4 pX0 = *(const float4*)xb;
  float4 pX1 = *(const float4*)(xb + 4);

  for (int s = 0; s < 18; ++s) {
    __syncthreads();  // prev MFMA reads done
    *(uint4*)&AH[rk][lb] = pAH;
    {
      float v[8] = {pX0.x, pX0.y, pX0.z, pX0.w, pX1.x, pX1.y, pX1.z, pX1.w};
      uint4 ph;
      cvt8(v, ph);
      *(uint4*)&Xh[rk][lb] = ph;
    }
    if (s < 17) {
      const int lo = (s + 1) * 32;
      pAH = *(const uint4*)(aHb + lo);
      pX0 = *(const float4*)(xb + lo);
      pX1 = *(const float4*)(xb + lo + 4);
    }
    __syncthreads();  // staged
    const int ar = wv * 16 + (lane & 15);
    const int ab = (lane >> 4) * 8;
    bf16x8 Ah = *(const bf16x8*)&AH[ar][ab];
#pragma unroll
    for (int dt = 0; dt < 4; ++dt) {
      const int br = dt * 16 + (lane & 15);
      bf16x8 Bh = *(const bf16x8*)&Xh[br][ab];
      acc[dt] = __builtin_amdgcn_mfma_f32_16x16x32_bf16(Ah, Bh, acc[dt], 0, 0, 0);
    }
  }

  // store raw out using PROBED positions
  float* ob = out + ((size_t)n * 64 + wv * 16) * DD + d0;
#pragma unroll
  for (int dt = 0; dt < 4; ++dt)
#pragma unroll
    for (int r = 0; r < 4; ++r)
      ob[(size_t)rowz[r] * DD + dt * 16 + colz[r]] = acc[dt][r];

  // fused per-(k, d-tile) sumsq partial (deterministic, no atomics)
#pragma unroll
  for (int r = 0; r < 4; ++r) {
    float s = 0.f;
#pragma unroll
    for (int dt = 0; dt < 4; ++dt) s = fmaf(acc[dt][r], acc[dt][r], s);
    s += __shfl_xor(s, 1, 64);
    s += __shfl_xor(s, 2, 64);
    s += __shfl_xor(s, 4, 64);
    s += __shfl_xor(s, 8, 64);
    if ((lane & 15) == 0)
      part[(size_t)b * 64 + wv * 16 + rowz[r]] = s;
  }
}

// ---------------------------------------------------------------------------
// kC3f: one block per (n,k) row. Lanes 0-11 read the 12 d-tile partials,
// shuffle-reduce, broadcast; scale row in place. Global norm over 64 unit
// rows == sqrt(64), so ginv = 1/8 (folded into 0.125).
// ---------------------------------------------------------------------------
__global__ __launch_bounds__(64) void kC3f(const float* __restrict__ part,
                                           float* __restrict__ out) {
  const int row = blockIdx.x;  // n*64 + k
  const int n = row >> 6, k = row & 63;
  const int t = threadIdx.x;
  float p = (t < 12) ? part[(size_t)(n * 12 + t) * 64 + k] : 0.f;
  p += __shfl_xor(p, 1, 64);
  p += __shfl_xor(p, 2, 64);
  p += __shfl_xor(p, 4, 64);
  p += __shfl_xor(p, 8, 64);
  const float ss = __shfl(p, 0, 64);
  const float sc = 0.125f / fmaxf(sqrtf(ss), EPSF);
  float4* o = (float4*)(out + (size_t)row * DD);
#pragma unroll
  for (int j = 0; j < 3; ++j) {
    float4 v = o[t + 64 * j];
    v.x *= sc; v.y *= sc; v.z *= sc; v.w *= sc;
    o[t + 64 * j] = v;
  }
}

// ---------------------------------------------------------------------------
extern "C" void kernel_launch(void* const* d_in, const int* in_sizes, int n_in,
                              void* d_out, int out_size, void* d_ws, size_t ws_size,
                              hipStream_t stream) {
  const float* x = (const float*)d_in[0];  // [64,768,24,24]
  const float* w = (const float*)d_in[1];  // [64,768]
  float* out = (float*)d_out;              // [64, 64*768]

  u16* attH = (u16*)d_ws;                    // [64,64,576] bf16 hi only
  u16* wfH = attH + (size_t)2359296;         // W fragments hi [4*24*64*8]
  float* part = (float*)(wfH + 49152);       // [768][64] sumsq partials
  // (scale buffer no longer needed)

  kW<<<24, 256, 0, stream>>>(w, wfH);
  kA<<<1152, 256, 0, stream>>>(x, wfH, attH);
  kB<<<768, 256, 0, stream>>>(x, attH, out, part);
  kC3f<<<4096, 64, 0, stream>>>(part, out);
}

// Round 12
// 58.773 us; speedup vs baseline: 1.2931x; 1.0032x over previous
//
#include <hip/hip_runtime.h>
#include <math.h>

#define EPSF 1e-12f
#define DD 768
#define LL 576

typedef unsigned short u16;
typedef __attribute__((ext_vector_type(8))) short bf16x8;
typedef __attribute__((ext_vector_type(4))) float f32x4;

__device__ __forceinline__ u16 bf16h(float v) {
  unsigned u = __float_as_uint(v);
  return (u16)((u + 0x7FFFu + ((u >> 16) & 1u)) >> 16);
}

// convert 8 floats -> packed bf16 (RNE) uint4
__device__ __forceinline__ void cvt8(const float* v, uint4& ph) {
  unsigned h[8];
#pragma unroll
  for (int i = 0; i < 8; ++i) {
    unsigned u = __float_as_uint(v[i]);
    h[i] = (u + 0x7FFFu + ((u >> 16) & 1u)) >> 16;
  }
  ph = make_uint4(h[0] | (h[1] << 16), h[2] | (h[3] << 16),
                  h[4] | (h[5] << 16), h[6] | (h[7] << 16));
}

// Layout probe: D1 = (bcast m-label) x (ones) -> 32*row ; D2 = (ones) x
// (bcast n-label) -> 32*col. True (row,col) per acc reg, any convention.
__device__ __forceinline__ void probe_layout(int lane, int* rowz, int* colz) {
  bf16x8 va, v1;
  const short ml = (short)bf16h((float)(lane & 15));
  const short on = (short)0x3F80;  // bf16(1.0)
#pragma unroll
  for (int e = 0; e < 8; ++e) { va[e] = ml; v1[e] = on; }
  f32x4 z = {0.f, 0.f, 0.f, 0.f};
  f32x4 D1 = __builtin_amdgcn_mfma_f32_16x16x32_bf16(va, v1, z, 0, 0, 0);
  f32x4 D2 = __builtin_amdgcn_mfma_f32_16x16x32_bf16(v1, va, z, 0, 0, 0);
#pragma unroll
  for (int r = 0; r < 4; ++r) {
    rowz[r] = (int)(D1[r] * 0.03125f + 0.5f);
    colz[r] = (int)(D2[r] * 0.03125f + 0.5f);
  }
}

// ---------------------------------------------------------------------------
// kW: pre-convert W into bf16 A-fragments (hi-only), fragment-major.
// ---------------------------------------------------------------------------
__global__ __launch_bounds__(256) void kW(const float* __restrict__ w,
                                          u16* __restrict__ wfH) {
  const int s = blockIdx.x;  // 0..23
  const int t = threadIdx.x;
  const int strip = t >> 6, lane = t & 63;
  const int k = strip * 16 + (lane & 15);
  const int d = s * 32 + (lane >> 4) * 8;
  float v[8];
  *(float4*)&v[0] = *(const float4*)(w + k * DD + d);
  *(float4*)&v[4] = *(const float4*)(w + k * DD + d + 4);
  uint4 ph;
  cvt8(v, ph);
  const size_t o = ((size_t)(strip * 24 + s) * 64 + lane) * 8;
  *(uint4*)(wfH + o) = ph;
}

// ---------------------------------------------------------------------------
// kA: per (n, 32-l tile): logits = W @ X, hi-only bf16.
// Round-12: DIRECT transposed cvt-write from staging registers (no raw fp32
// LDS round-trip), 2 barriers/step. Write conflicts: per wave, cols = one
// 8-slot; rows {j,4+j,..}: sigma(row)=(row>>3)&3 gives each of the 4 rows per
// bank-class a distinct dword-quad -> 32 banks, 2 lanes/dword (free).
// Read pattern unchanged from verified rounds 4-11.
// ---------------------------------------------------------------------------
__global__ __launch_bounds__(256) void kA(const float* __restrict__ x,
                                          const u16* __restrict__ wfH,
                                          u16* __restrict__ attH) {
  __shared__ __align__(16) char pool[9216];
  u16 (*Xh)[40] = (u16(*)[40])pool;            // [32l][32d swizzled]+pad
  float (*Ls)[36] = (float(*)[36])pool;        // [64k][32l+4] aliases pool
  __shared__ float red8[8][32];
  __shared__ float colinv[32], colmax[32], colscale[32];

  const int b = blockIdx.x;
  const int n = b / 18, l0 = (b % 18) * 32;
  const int t = threadIdx.x;
  const int wv = t >> 6, lane = t & 63;

  int rowz[4], colz[4];
  probe_layout(lane, rowz, colz);

  f32x4 z = {0.f, 0.f, 0.f, 0.f};
  f32x4 acc[2] = {z, z};
  float ssq4[4] = {0.f, 0.f, 0.f, 0.f};

  const int xd = t >> 3;        // 0..31 staging d (column in Xh)
  const int xl = (t & 7) * 4;   // staging l quad (rows xl..xl+3)
  // rows xl..xl+3 lie in one octet -> sigma constant per thread:
  const int sig = (xl >> 3) & 3;
  const int xidx = (((xd >> 3) ^ sig) << 3) + (xd & 7);  // swizzled u16 col

  const float* xbase = x + (size_t)n * DD * LL + l0;
  const u16* wfHp = wfH + ((size_t)wv * 24 * 64 + lane) * 8;

  float4 pre = *(const float4*)(xbase + (size_t)xd * LL + xl);

  for (int s = 0; s < 24; ++s) {
    __syncthreads();  // prev MFMA Xh-reads done
    {
      const float pv[4] = {pre.x, pre.y, pre.z, pre.w};
#pragma unroll
      for (int j = 0; j < 4; ++j) {
        Xh[xl + j][xidx] = bf16h(pv[j]);
        ssq4[j] = fmaf(pv[j], pv[j], ssq4[j]);
      }
    }
    if (s < 23)
      pre = *(const float4*)(xbase + (size_t)((s + 1) * 32 + xd) * LL + xl);
    bf16x8 Ah = *(const bf16x8*)(wfHp + (size_t)s * 512);
    __syncthreads();  // Xh ready
#pragma unroll
    for (int lt = 0; lt < 2; ++lt) {
      const int bl = lt * 16 + (lane & 15);
      const int pb = ((lane >> 4) ^ ((bl >> 3) & 3)) * 8;
      bf16x8 Bh = *(const bf16x8*)&Xh[bl][pb];
      acc[lt] = __builtin_amdgcn_mfma_f32_16x16x32_bf16(Ah, Bh, acc[lt], 0, 0, 0);
    }
  }

  // ssq reduce across xd-within-wave (lane bits 3,4,5); cg = lane&7
#pragma unroll
  for (int i = 0; i < 4; ++i) {
    ssq4[i] += __shfl_xor(ssq4[i], 8, 64);
    ssq4[i] += __shfl_xor(ssq4[i], 16, 64);
    ssq4[i] += __shfl_xor(ssq4[i], 32, 64);
  }
  if (lane < 8) {
#pragma unroll
    for (int i = 0; i < 4; ++i) red8[wv][lane * 4 + i] = ssq4[i];
  }
  __syncthreads();  // red8 ready; also guards Ls scatter vs last MFMA reads
  if (t < 32)
    colinv[t] =
        1.f / fmaxf(sqrtf(red8[0][t] + red8[1][t] + red8[2][t] + red8[3][t]), EPSF);
  // scatter raw logits using PROBED positions (Ls aliases dead staging pool)
#pragma unroll
  for (int lt = 0; lt < 2; ++lt)
#pragma unroll
    for (int r = 0; r < 4; ++r)
      Ls[wv * 16 + rowz[r]][lt * 16 + colz[r]] = acc[lt][r];
  __syncthreads();

  // softmax over k per column; thread (q=t>>5, cl=t&31) owns 8 k's
  const int cl = t & 31, q = t >> 5;
  const float cinv = colinv[cl];
  float sv[8];
  float m = -1e30f;
#pragma unroll
  for (int i = 0; i < 8; ++i) {
    const float vv = Ls[q * 8 + i][cl] * cinv;
    sv[i] = vv;
    m = fmaxf(m, vv);
  }
  red8[q][cl] = m;
  __syncthreads();
  if (t < 32) {
    float mm = red8[0][t];
#pragma unroll
    for (int j = 1; j < 8; ++j) mm = fmaxf(mm, red8[j][t]);
    colmax[t] = mm;
  }
  __syncthreads();
  const float M = colmax[cl];
  float ssum = 0.f;
#pragma unroll
  for (int i = 0; i < 8; ++i) {
    const float e = __expf(sv[i] - M);
    sv[i] = e;
    ssum += e;
  }
  red8[q][cl] = ssum;
  __syncthreads();
  if (t < 32) {
    float ss = red8[0][t];
#pragma unroll
    for (int j = 1; j < 8; ++j) ss += red8[j][t];
    colscale[t] = colinv[t] / ss;
  }
  __syncthreads();
  const float cs = colscale[cl];
  u16* aH = attH + (size_t)n * 64 * LL + l0 + cl;
#pragma unroll
  for (int i = 0; i < 8; ++i) {
    const int k = q * 8 + i;
    aH[(size_t)k * LL] = bf16h(sv[i] * cs);
  }
}

// ---------------------------------------------------------------------------
// kB: per (n, 64-d tile): out[k][d] = sum_l att'[k][l] * x[d][l].
// Hi-only bf16 MFMA. Reg-prefetched staging. Probe-based output positions.
// Fused per-(k, d-tile) sumsq partials -> part[b][k] (deterministic).
// ---------------------------------------------------------------------------
__global__ __launch_bounds__(256) void kB(const float* __restrict__ x,
                                          const u16* __restrict__ attH,
                                          float* __restrict__ out,
                                          float* __restrict__ part) {
  __shared__ __align__(16) u16 AH[64][40];
  __shared__ __align__(16) u16 Xh[64][40];
  const int b = blockIdx.x;
  const int n = b / 12, d0 = (b % 12) * 64;
  const int t = threadIdx.x;
  const int wv = t >> 6, lane = t & 63;

  int rowz[4], colz[4];
  probe_layout(lane, rowz, colz);

  f32x4 z = {0.f, 0.f, 0.f, 0.f};
  f32x4 acc[4] = {z, z, z, z};

  const int rk = t >> 2;       // staging row 0..63
  const int lb = (t & 3) * 8;  // l offset 0,8,16,24

  const u16* aHb = attH + ((size_t)n * 64 + rk) * LL + lb;
  const float* xb = x + ((size_t)n * DD + d0 + rk) * LL + lb;

  uint4 pAH = *(const uint4*)aHb;
  float4 pX0 = *(const float4*)xb;
  float4 pX1 = *(const float4*)(xb + 4);

  for (int s = 0; s < 18; ++s) {
    __syncthreads();  // prev MFMA reads done
    *(uint4*)&AH[rk][lb] = pAH;
    {
      float v[8] = {pX0.x, pX0.y, pX0.z, pX0.w, pX1.x, pX1.y, pX1.z, pX1.w};
      uint4 ph;
      cvt8(v, ph);
      *(uint4*)&Xh[rk][lb] = ph;
    }
    if (s < 17) {
      const int lo = (s + 1) * 32;
      pAH = *(const uint4*)(aHb + lo);
      pX0 = *(const float4*)(xb + lo);
      pX1 = *(const float4*)(xb + lo + 4);
    }
    __syncthreads();  // staged
    const int ar = wv * 16 + (lane & 15);
    const int ab = (lane >> 4) * 8;
    bf16x8 Ah = *(const bf16x8*)&AH[ar][ab];
#pragma unroll
    for (int dt = 0; dt < 4; ++dt) {
      const int br = dt * 16 + (lane & 15);
      bf16x8 Bh = *(const bf16x8*)&Xh[br][ab];
      acc[dt] = __builtin_amdgcn_mfma_f32_16x16x32_bf16(Ah, Bh, acc[dt], 0, 0, 0);
    }
  }

  // store raw out using PROBED positions
  float* ob = out + ((size_t)n * 64 + wv * 16) * DD + d0;
#pragma unroll
  for (int dt = 0; dt < 4; ++dt)
#pragma unroll
    for (int r = 0; r < 4; ++r)
      ob[(size_t)rowz[r] * DD + dt * 16 + colz[r]] = acc[dt][r];

  // fused per-(k, d-tile) sumsq partial (deterministic, no atomics)
#pragma unroll
  for (int r = 0; r < 4; ++r) {
    float s = 0.f;
#pragma unroll
    for (int dt = 0; dt < 4; ++dt) s = fmaf(acc[dt][r], acc[dt][r], s);
    s += __shfl_xor(s, 1, 64);
    s += __shfl_xor(s, 2, 64);
    s += __shfl_xor(s, 4, 64);
    s += __shfl_xor(s, 8, 64);
    if ((lane & 15) == 0)
      part[(size_t)b * 64 + wv * 16 + rowz[r]] = s;
  }
}

// ---------------------------------------------------------------------------
// kC3f: one block per (n,k) row. Lanes 0-11 read the 12 d-tile partials,
// shuffle-reduce, broadcast; scale row in place. Global norm over 64 unit
// rows == sqrt(64), so ginv = 1/8 (folded into 0.125).
// ---------------------------------------------------------------------------
__global__ __launch_bounds__(64) void kC3f(const float* __restrict__ part,
                                           float* __restrict__ out) {
  const int row = blockIdx.x;  // n*64 + k
  const int n = row >> 6, k = row & 63;
  const int t = threadIdx.x;
  float p = (t < 12) ? part[(size_t)(n * 12 + t) * 64 + k] : 0.f;
  p += __shfl_xor(p, 1, 64);
  p += __shfl_xor(p, 2, 64);
  p += __shfl_xor(p, 4, 64);
  p += __shfl_xor(p, 8, 64);
  const float ss = __shfl(p, 0, 64);
  const float sc = 0.125f / fmaxf(sqrtf(ss), EPSF);
  float4* o = (float4*)(out + (size_t)row * DD);
#pragma unroll
  for (int j = 0; j < 3; ++j) {
    float4 v = o[t + 64 * j];
    v.x *= sc; v.y *= sc; v.z *= sc; v.w *= sc;
    o[t + 64 * j] = v;
  }
}

// ---------------------------------------------------------------------------
extern "C" void kernel_launch(void* const* d_in, const int* in_sizes, int n_in,
                              void* d_out, int out_size, void* d_ws, size_t ws_size,
                              hipStream_t stream) {
  const float* x = (const float*)d_in[0];  // [64,768,24,24]
  const float* w = (const float*)d_in[1];  // [64,768]
  float* out = (float*)d_out;              // [64, 64*768]

  u16* attH = (u16*)d_ws;                    // [64,64,576] bf16 hi only
  u16* wfH = attH + (size_t)2359296;         // W fragments hi [4*24*64*8]
  float* part = (float*)(wfH + 49152);       // [768][64] sumsq partials

  kW<<<24, 256, 0, stream>>>(w, wfH);
  kA<<<1152, 256, 0, stream>>>(x, wfH, attH);
  kB<<<768, 256, 0, stream>>>(x, attH, out, part);
  kC3f<<<4096, 64, 0, stream>>>(part, out);
}